// Round 7
// baseline (1411.222 us; speedup 1.0000x reference)
//
#include <hip/hip_runtime.h>

// Llama4TextExperts: E=8, H=2048, D=2048, 4096 tokens/expert.
// out = (up * silu(gate)) @ W2,  [gate|up] = x @ W1
// Round 7: 256x256 tile, BK=32, 16 waves (1024 thr, 4 waves/SIMD), 32x32x16
// MFMA, 4-deep LDS ring (128 KiB), stage-ahead-3 with vmcnt(4)/tile, counted
// lgkm waits, 2 barriers/tile. SwiGLU fused via 32-col gate/up interleave.

#define E_EXPERTS 8
#define TPE 4096
#define KD 2048

typedef __bf16 bf16_t;
typedef __bf16 bf16x4 __attribute__((ext_vector_type(4)));
typedef __bf16 bf16x8 __attribute__((ext_vector_type(8)));
typedef float f32x16 __attribute__((ext_vector_type(16)));

#define GLOAD16(src, dst)                                               \
  __builtin_amdgcn_global_load_lds(                                     \
      (const __attribute__((address_space(1))) void*)(src),             \
      (__attribute__((address_space(3))) void*)(dst), 16, 0, 0)

// ---------------- pass 1: x f32 -> bf16 ----------------
__global__ void cvt_f32_bf16_kernel(const float* __restrict__ in,
                                    bf16_t* __restrict__ out, long n4) {
  long i = (long)blockIdx.x * blockDim.x + threadIdx.x;
  const long stride = (long)gridDim.x * blockDim.x;
  const float4* in4 = (const float4*)in;
  bf16x4* out4 = (bf16x4*)out;
  for (; i < n4; i += stride) {
    float4 v = in4[i];
    bf16x4 o = {(bf16_t)v.x, (bf16_t)v.y, (bf16_t)v.z, (bf16_t)v.w};
    out4[i] = o;
  }
}

// ------- pass 2: per-expert transpose+convert: W[K][N] f32 -> WT[N][K] bf16 -------
__global__ void transpose_cvt_kernel(const float* __restrict__ W,
                                     bf16_t* __restrict__ WT, int K, int N) {
  __shared__ float tile[64][65];
  const int e = blockIdx.z;
  const float* Wp = W + (size_t)e * K * N;
  bf16_t* Tp = WT + (size_t)e * N * K;
  const int n0 = blockIdx.x * 64, k0 = blockIdx.y * 64;
  const int rr = threadIdx.x >> 4;
  const int cc = (threadIdx.x & 15) * 4;
#pragma unroll
  for (int p = 0; p < 4; ++p) {
    const int k = rr + p * 16;
    float4 v = *(const float4*)(Wp + (size_t)(k0 + k) * N + n0 + cc);
    tile[k][cc + 0] = v.x;
    tile[k][cc + 1] = v.y;
    tile[k][cc + 2] = v.z;
    tile[k][cc + 3] = v.w;
  }
  __syncthreads();
#pragma unroll
  for (int p = 0; p < 4; ++p) {
    const int n = rr + p * 16;
    bf16x4 o;
#pragma unroll
    for (int j = 0; j < 4; ++j) o[j] = (bf16_t)tile[cc + j][n];
    *(bf16x4*)(Tp + (size_t)(n0 + n) * K + k0 + cc) = o;
  }
}

// ---------------- 256x256 BK=32 16-wave grouped GEMM ----------------
// Wave grid 8(M) x 2(N): per wave 32 rows x 128 cols = 2x2... rows: wm=wid>>1
// (32 rows), cols: wn=wid&1 (128 cols = 4 frags of 32). acc = 4 x f32x16.
// Per K-tile t (ring buf bR=t&3):
//  P1: ds_read A(2),B0..B3(8); gload stage A,B(t+3)->buf (bR+3)&3;
//      W6->A,B0: MFMA q0; W4->B1: MFMA q1; BAR.
//  P2: W2->B2: MFMA q2; W0->B3: MFMA q3; VMC4; BAR.
// Safety: stage(t+3) dest ring slot == slot of tile t-1, whose readers all
// drained at t-1.P2 (W0) and sealed by t-1.P2 BAR. vmcnt(4)@t.P2 keeps the 4
// newest loads (pairs t+2,t+3) => everything older (pair t+1) landed before
// t+1.P1's ds_reads; BAR broadcasts to all waves. lgkm audit in-line below.
template <bool FUSED, int NTN>
__global__ __launch_bounds__(1024, 4) void moe_gemm32_kernel(
    const bf16_t* __restrict__ A, const bf16_t* __restrict__ Bm,
    void* __restrict__ Cout) {
  constexpr int NT = KD / 32;  // 64 K-tiles

  __shared__ alignas(16) bf16_t As[4][256][32];
  __shared__ alignas(16) bf16_t Bs[4][256][32];

  // XCD swizzle (grid%8==0): one expert per XCD; intra-XCD row-major.
  const int NWG = gridDim.x;
  int wg = blockIdx.x;
  wg = (wg & 7) * (NWG >> 3) + (wg >> 3);
  const int e = wg / (16 * NTN);
  const int rem = wg % (16 * NTN);
  const int mt = rem / NTN, ntile = rem % NTN;
  const int t0 = mt * 256, n0 = ntile * 256;

  const int tid = threadIdx.x;
  const int wid = tid >> 6, lane = tid & 63;
  const int wm = wid >> 1, wn = wid & 1;

  const bf16_t* Ae = A + (size_t)e * TPE * KD + (size_t)t0 * KD;
  const bf16_t* Be = Bm + (size_t)e * (size_t)(FUSED ? 4096 : 2048) * KD;

  // staging: each wave stages 16 rows (1 KiB): lane -> row slr=l>>2, chunk
  // l&3; source chunk pre-swizzled by ^(row&3) so linear LDS == swizzled.
  const int slr = lane >> 2;
  const int sel = ((lane & 3) ^ (slr & 3)) * 8;

  auto stageA = [&](int kt, int bD) {
    const int k0 = (kt & (NT - 1)) * 32;
    const int r0 = wid * 16;
    GLOAD16(Ae + (size_t)(r0 + slr) * KD + k0 + sel, &As[bD][r0][0]);
  };
  auto stageB = [&](int kt, int bD) {
    const int k0 = (kt & (NT - 1)) * 32;
    const int r0 = wid * 16;
    const int R = n0 + r0 + slr;
    int srow;
    if constexpr (FUSED)  // 32-col gate/up interleave of W1^T virtual rows
      srow = ((R >> 6) << 5) + (R & 31) + ((R >> 5) & 1) * 2048;
    else
      srow = R;
    GLOAD16(Be + (size_t)srow * KD + k0 + sel, &Bs[bD][r0][0]);
  };

  const int l31 = lane & 31, l3 = lane & 3, hk = lane >> 5;

  f32x16 acc[4] = {};       // 4 n-frags of 32x32 (literal-indexed only)
  bf16x8 aS[2];             // A k-slices s=0,1
  bf16x8 b0[2], b1[2], b2[2], b3[2];

  // A fragment: row = wm*32 + (lane&31); k-octet g = 2s+hk; chunk g^(row&3)
  auto readA = [&](int bR) {
    const int row = wm * 32 + l31;
#pragma unroll
    for (int s = 0; s < 2; ++s) {
      const int ch = ((2 * s + hk) ^ l3) * 8;
      aS[s] = *(const bf16x8*)&As[bR][row][ch];
    }
  };
  auto readB = [&](int bR, int qn, bf16x8 (&dst)[2]) {
    const int row = wn * 128 + qn * 32 + l31;
#pragma unroll
    for (int s = 0; s < 2; ++s) {
      const int ch = ((2 * s + hk) ^ l3) * 8;
      dst[s] = *(const bf16x8*)&Bs[bR][row][ch];
    }
  };

#define W6 asm volatile("s_waitcnt lgkmcnt(6)" ::: "memory")
#define W4 asm volatile("s_waitcnt lgkmcnt(4)" ::: "memory")
#define W2 asm volatile("s_waitcnt lgkmcnt(2)" ::: "memory")
#define W0 asm volatile("s_waitcnt lgkmcnt(0)" ::: "memory")
#define VMC4 asm volatile("s_waitcnt vmcnt(4)" ::: "memory")
#define BAR __builtin_amdgcn_s_barrier()
#define SCHED0 __builtin_amdgcn_sched_barrier(0)
#define PRIO1 __builtin_amdgcn_s_setprio(1)
#define PRIO0 __builtin_amdgcn_s_setprio(0)
#define MMA(Q, B)                                                     \
  do {                                                                \
    acc[Q] = __builtin_amdgcn_mfma_f32_32x32x16_bf16(aS[0], B[0],     \
                                                     acc[Q], 0, 0, 0); \
    acc[Q] = __builtin_amdgcn_mfma_f32_32x32x16_bf16(aS[1], B[1],     \
                                                     acc[Q], 0, 0, 0); \
  } while (0)

  // prologue: stage tiles 0,1,2 into ring slots 0,1,2; pair 0 must land.
  stageA(0, 0); stageB(0, 0);
  stageA(1, 1); stageB(1, 1);
  stageA(2, 2); stageB(2, 2);
  VMC4;  // 6 outstanding -> <=4: pair 0 landed
  BAR; SCHED0;

  int bR = 0;
  for (int t = 0; t < NT; ++t) {
    const int bD = (bR + 3) & 3;
    // P1 — lgkm: issue A(2),B0(2),B1(2),B2(2),B3(2) = 10
    readA(bR);
    readB(bR, 0, b0);
    readB(bR, 1, b1);
    readB(bR, 2, b2);
    readB(bR, 3, b3);
    stageA(t + 3, bD);
    stageB(t + 3, bD);
    W6; SCHED0;             // drains A,B0 (keeps B1,B2,B3)
    PRIO1; MMA(0, b0); PRIO0;
    W4; SCHED0;             // drains B1
    PRIO1; MMA(1, b1); PRIO0;
    BAR;
    // P2
    W2; SCHED0;             // drains B2
    PRIO1; MMA(2, b2); PRIO0;
    W0; SCHED0;             // drains B3
    PRIO1; MMA(3, b3); PRIO0;
    VMC4;                   // keeps pairs (t+2),(t+3); (t+1) provably landed
    BAR; SCHED0;
    bR = (bR + 1) & 3;
  }

  // Epilogue. 32x32 C/D: row=(reg&3)+8*(reg>>2)+4*(lane>>5), col=lane&31.
  const int rbase = t0 + wm * 32;
  if constexpr (FUSED) {
    bf16_t* Cp = (bf16_t*)Cout + (size_t)e * TPE * KD;
    const int d0 = ((n0 + wn * 128) >> 1) + l31;
#pragma unroll
    for (int p = 0; p < 2; ++p) {
#pragma unroll
      for (int reg = 0; reg < 16; ++reg) {
        const int row = rbase + (reg & 3) + 8 * (reg >> 2) + 4 * hk;
        const int col = d0 + p * 32;
        const float g = acc[2 * p][reg], u = acc[2 * p + 1][reg];
        const float s = 1.0f / (1.0f + __expf(-g));
        Cp[(size_t)row * KD + col] = (bf16_t)(u * g * s);
      }
    }
  } else {
    float* Cp = (float*)Cout + (size_t)e * TPE * KD;
#pragma unroll
    for (int q = 0; q < 4; ++q) {
#pragma unroll
      for (int reg = 0; reg < 16; ++reg) {
        const int row = rbase + (reg & 3) + 8 * (reg >> 2) + 4 * hk;
        const int col = n0 + wn * 128 + q * 32 + l31;
        Cp[(size_t)row * KD + col] = acc[q][reg];
      }
    }
  }
#undef W6
#undef W4
#undef W2
#undef W0
#undef VMC4
#undef BAR
#undef SCHED0
#undef PRIO1
#undef PRIO0
#undef MMA
}

extern "C" void kernel_launch(void* const* d_in, const int* in_sizes, int n_in,
                              void* d_out, int out_size, void* d_ws,
                              size_t ws_size, hipStream_t stream) {
  const float* hs = (const float*)d_in[0];  // (32768, 2048)
  const float* w1 = (const float*)d_in[1];  // (8, 2048, 4096)
  const float* w2 = (const float*)d_in[2];  // (8, 2048, 2048)

  // ws layout (448 MiB):
  //   xb  bf16 [32768][2048]     128 MiB @ 0
  //   w1t bf16 [8][4096][2048]   128 MiB @ 128M
  //   w2t bf16 [8][2048][2048]    64 MiB @ 256M
  //   act bf16 [8][4096][2048]   128 MiB @ 320M
  char* ws = (char*)d_ws;
  bf16_t* xb = (bf16_t*)(ws);
  bf16_t* w1t = (bf16_t*)(ws + (size_t)134217728);
  bf16_t* w2t = (bf16_t*)(ws + (size_t)268435456);
  bf16_t* act = (bf16_t*)(ws + (size_t)335544320);

  const long n4 = (long)E_EXPERTS * TPE * KD / 4;
  cvt_f32_bf16_kernel<<<2048, 256, 0, stream>>>(hs, xb, n4);
  transpose_cvt_kernel<<<dim3(64, 32, 8), 256, 0, stream>>>(w1, w1t, 2048, 4096);
  transpose_cvt_kernel<<<dim3(32, 32, 8), 256, 0, stream>>>(w2, w2t, 2048, 2048);
  // G1: virtual N=4096 (gate/up 32-col interleave) -> NTN=16; grid 2048
  moe_gemm32_kernel<true, 16><<<2048, 1024, 0, stream>>>(xb, w1t, (void*)act);
  // G2: N=2048 -> NTN=8; grid 1024
  moe_gemm32_kernel<false, 8><<<1024, 1024, 0, stream>>>(act, w2t, d_out);
}

// Round 8
// 1069.123 us; speedup vs baseline: 1.3200x; 1.3200x over previous
//
#include <hip/hip_runtime.h>

// Llama4TextExperts: E=8, H=2048, D=2048, 4096 tokens/expert.
// out = (up * silu(gate)) @ W2,  [gate|up] = x @ W1
// Round 8: 128x256 tile, BK=32, 8 waves, 3-deep LDS ring (72 KiB) ->
// 2 independent blocks/CU (TLP across barrier domains). Interleaved LDS rows
// (two k-half rows per 128B phys row) restore the proven 8-chunk XOR swizzle.
// 2 phases/tile, W0 counted... full-drain waits, vmcnt(3), 1 barrier/tile.

#define E_EXPERTS 8
#define TPE 4096
#define KD 2048

typedef __bf16 bf16_t;
typedef __bf16 bf16x4 __attribute__((ext_vector_type(4)));
typedef __bf16 bf16x8 __attribute__((ext_vector_type(8)));
typedef float f32x4 __attribute__((ext_vector_type(4)));

#define GLOAD16(src, dst)                                               \
  __builtin_amdgcn_global_load_lds(                                     \
      (const __attribute__((address_space(1))) void*)(src),             \
      (__attribute__((address_space(3))) void*)(dst), 16, 0, 0)

// ---------------- pass 1: x f32 -> bf16 ----------------
__global__ void cvt_f32_bf16_kernel(const float* __restrict__ in,
                                    bf16_t* __restrict__ out, long n4) {
  long i = (long)blockIdx.x * blockDim.x + threadIdx.x;
  const long stride = (long)gridDim.x * blockDim.x;
  const float4* in4 = (const float4*)in;
  bf16x4* out4 = (bf16x4*)out;
  for (; i < n4; i += stride) {
    float4 v = in4[i];
    bf16x4 o = {(bf16_t)v.x, (bf16_t)v.y, (bf16_t)v.z, (bf16_t)v.w};
    out4[i] = o;
  }
}

// ------- pass 2: per-expert transpose+convert: W[K][N] f32 -> WT[N][K] bf16 -------
__global__ void transpose_cvt_kernel(const float* __restrict__ W,
                                     bf16_t* __restrict__ WT, int K, int N) {
  __shared__ float tile[64][65];
  const int e = blockIdx.z;
  const float* Wp = W + (size_t)e * K * N;
  bf16_t* Tp = WT + (size_t)e * N * K;
  const int n0 = blockIdx.x * 64, k0 = blockIdx.y * 64;
  const int rr = threadIdx.x >> 4;
  const int cc = (threadIdx.x & 15) * 4;
#pragma unroll
  for (int p = 0; p < 4; ++p) {
    const int k = rr + p * 16;
    float4 v = *(const float4*)(Wp + (size_t)(k0 + k) * N + n0 + cc);
    tile[k][cc + 0] = v.x;
    tile[k][cc + 1] = v.y;
    tile[k][cc + 2] = v.z;
    tile[k][cc + 3] = v.w;
  }
  __syncthreads();
#pragma unroll
  for (int p = 0; p < 4; ++p) {
    const int n = rr + p * 16;
    bf16x4 o;
#pragma unroll
    for (int j = 0; j < 4; ++j) o[j] = (bf16_t)tile[cc + j][n];
    *(bf16x4*)(Tp + (size_t)(n0 + n) * K + k0 + cc) = o;
  }
}

// ---------------- 128x256 BK=32 2-blocks/CU grouped GEMM ----------------
// LDS phys layout (A, 128 tile rows): phys row p in [0,64), 128B: logical
// chunk c in [0,8): half h=c>>2, k-octet kg=c&3 -> tile row p+64h, k kg*8..+8.
// Stored at chunk c^(p&7) (involution; same XOR on stage-source and read).
// B: 256 tile rows -> 128 phys rows, h = R>>7.
// Waves 2(M)x4(N), per wave 64x64: A frags m0..3, B frags (2q+j) of 16 cols.
// Per K-tile t (slot s=t%3, s2=(s+2)%3 = slot of t-1, readers drained):
//  P1: ds_read A(4)+B(q=0: 2); stage A,B(t+2)->s2 (3 gloads); W0 SCHED0;
//      8 MFMA (acc[m][0],[1]).
//  P2: ds_read B(q=1: 2) (reuse regs, in-order safe); W0 SCHED0;
//      8 MFMA (acc[m][2],[3]); VMC3; BAR.
// vmcnt audit: at P2 end outstanding = {t+1(3), t+2(3)}; VMC3 keeps t+2 ->
// t+1 landed before its reads at t+1.P1 (sealed by BAR). Overwrite audit:
// stage->slot(t-1); all waves' t-1 reads drained by their (t-1).P2 W0, and we
// are past (t-1)'s end-BAR when issuing.
template <bool FUSED, int NTN>
__global__ __launch_bounds__(512, 4) void moe_gemm_tlp_kernel(
    const bf16_t* __restrict__ A, const bf16_t* __restrict__ Bm,
    void* __restrict__ Cout) {
  constexpr int NT = KD / 32;  // 64 K-tiles

  __shared__ alignas(16) bf16_t As[3][64][64];    // 24 KiB
  __shared__ alignas(16) bf16_t Bs[3][128][64];   // 48 KiB

  // bijective XCD swizzle (grid%8==0): one expert per XCD; intra-XCD
  // row-major (A-panel shared by consecutive blocks).
  const int NWG = gridDim.x;
  int wg = blockIdx.x;
  wg = (wg & 7) * (NWG >> 3) + (wg >> 3);
  const int e = wg / (32 * NTN);
  const int rem = wg % (32 * NTN);
  const int mt = rem / NTN, ntile = rem % NTN;
  const int t0 = mt * 128, n0 = ntile * 256;

  const int tid = threadIdx.x;
  const int wid = tid >> 6, lane = tid & 63;
  const int wr = wid >> 2, wc = wid & 3;  // 2(M) x 4(N); 64x64 per wave

  const bf16_t* Ae = A + (size_t)e * TPE * KD + (size_t)t0 * KD;
  const bf16_t* Be = Bm + (size_t)e * (size_t)(FUSED ? 4096 : 2048) * KD;

  // ---- staging source (per-lane constants) ----
  const int sp = lane >> 3;  // phys-row offset within 8-row gload
  const int lc = lane & 7;   // written chunk

  // A: phys p = wid*8+sp; logical c = lc^(p&7); tile row = p+64*(c>>2)
  const int pA = wid * 8 + sp;
  const int cA = lc ^ (pA & 7);
  const bf16_t* aSrc = Ae + (size_t)(pA + 64 * (cA >> 2)) * KD + (cA & 3) * 8;

  // B: two gloads, phys p = wid*16 + i*8 + sp
  const bf16_t* bSrc[2];
#pragma unroll
  for (int i = 0; i < 2; ++i) {
    const int p = wid * 16 + i * 8 + sp;
    const int c = lc ^ (p & 7);
    const int R = n0 + p + 128 * (c >> 2);
    int srow;
    if constexpr (FUSED)
      srow = ((R >> 5) << 4) + (R & 15) + ((R >> 4) & 1) * 2048;
    else
      srow = R;
    bSrc[i] = Be + (size_t)srow * KD + (c & 3) * 8;
  }

  auto stageA = [&](int kt, int slot) {
    const int k0 = (kt & (NT - 1)) * 32;
    GLOAD16(aSrc + k0, &As[slot][wid * 8][0]);
  };
  auto stageB = [&](int kt, int slot) {
    const int k0 = (kt & (NT - 1)) * 32;
#pragma unroll
    for (int i = 0; i < 2; ++i)
      GLOAD16(bSrc[i] + k0, &Bs[slot][wid * 16 + i * 8][0]);
  };

  // ---- fragment reads ----
  const int la = lane & 15, kg4 = lane >> 4;

  f32x4 acc[4][4] = {};
  bf16x8 am[4];
  bf16x8 bn[2];

  auto readA = [&](int slot) {
#pragma unroll
    for (int m = 0; m < 4; ++m) {
      const int r = wr * 64 + m * 16 + la;  // [0,128)
      const int p = r & 63, h = r >> 6;
      const int c = (h * 4 + kg4) ^ (p & 7);
      am[m] = *(const bf16x8*)&As[slot][p][c * 8];
    }
  };
  auto readB = [&](int slot, int q) {
#pragma unroll
    for (int j = 0; j < 2; ++j) {
      const int R = wc * 64 + q * 32 + j * 16 + la;  // [0,256)
      const int p = R & 127, h = R >> 7;
      const int c = (h * 4 + kg4) ^ (p & 7);
      bn[j] = *(const bf16x8*)&Bs[slot][p][c * 8];
    }
  };

#define W0 asm volatile("s_waitcnt lgkmcnt(0)" ::: "memory")
#define VMC3 asm volatile("s_waitcnt vmcnt(3)" ::: "memory")
#define BAR __builtin_amdgcn_s_barrier()
#define SCHED0 __builtin_amdgcn_sched_barrier(0)
#define PRIO1 __builtin_amdgcn_s_setprio(1)
#define PRIO0 __builtin_amdgcn_s_setprio(0)

  // prologue: tiles 0,1 -> slots 0,1; drain tile0 (keep tile1 in flight)
  stageA(0, 0); stageB(0, 0);
  stageA(1, 1); stageB(1, 1);
  VMC3;
  BAR; SCHED0;

  int s = 0, s2 = 2;
  for (int t = 0; t < NT; ++t) {
    // P1
    readA(s);
    readB(s, 0);
    stageA(t + 2, s2);
    stageB(t + 2, s2);
    W0; SCHED0;
    PRIO1;
#pragma unroll
    for (int m = 0; m < 4; ++m) {
      acc[m][0] = __builtin_amdgcn_mfma_f32_16x16x32_bf16(am[m], bn[0],
                                                          acc[m][0], 0, 0, 0);
      acc[m][1] = __builtin_amdgcn_mfma_f32_16x16x32_bf16(am[m], bn[1],
                                                          acc[m][1], 0, 0, 0);
    }
    PRIO0;
    // P2
    readB(s, 1);
    W0; SCHED0;
    PRIO1;
#pragma unroll
    for (int m = 0; m < 4; ++m) {
      acc[m][2] = __builtin_amdgcn_mfma_f32_16x16x32_bf16(am[m], bn[0],
                                                          acc[m][2], 0, 0, 0);
      acc[m][3] = __builtin_amdgcn_mfma_f32_16x16x32_bf16(am[m], bn[1],
                                                          acc[m][3], 0, 0, 0);
    }
    PRIO0;
    VMC3;
    BAR; SCHED0;
    s = (s == 2) ? 0 : s + 1;
    s2 = (s2 == 2) ? 0 : s2 + 1;
  }

  // Epilogue. C/D layout: row=(lane>>4)*4+r, col=lane&15 (verified).
  const int rbase = t0 + wr * 64;
  if constexpr (FUSED) {
    bf16_t* Cp = (bf16_t*)Cout + (size_t)e * TPE * KD;
    const int jb = (n0 >> 1) + 32 * wc;  // frag 2q=gate, 2q+1=up, same cols
#pragma unroll
    for (int m = 0; m < 4; ++m)
#pragma unroll
      for (int q = 0; q < 2; ++q)
#pragma unroll
        for (int r = 0; r < 4; ++r) {
          const int row = rbase + m * 16 + kg4 * 4 + r;
          const int col = jb + q * 16 + la;
          const float g = acc[m][2 * q][r], u = acc[m][2 * q + 1][r];
          const float sg = 1.0f / (1.0f + __expf(-g));
          Cp[(size_t)row * KD + col] = (bf16_t)(u * g * sg);
        }
  } else {
    float* Cp = (float*)Cout + (size_t)e * TPE * KD;
#pragma unroll
    for (int m = 0; m < 4; ++m)
#pragma unroll
      for (int n = 0; n < 4; ++n)
#pragma unroll
        for (int r = 0; r < 4; ++r) {
          const int row = rbase + m * 16 + kg4 * 4 + r;
          const int col = n0 + wc * 64 + n * 16 + la;
          Cp[(size_t)row * KD + col] = acc[m][n][r];
        }
  }
#undef W0
#undef VMC3
#undef BAR
#undef SCHED0
#undef PRIO1
#undef PRIO0
}

extern "C" void kernel_launch(void* const* d_in, const int* in_sizes, int n_in,
                              void* d_out, int out_size, void* d_ws,
                              size_t ws_size, hipStream_t stream) {
  const float* hs = (const float*)d_in[0];  // (32768, 2048)
  const float* w1 = (const float*)d_in[1];  // (8, 2048, 4096)
  const float* w2 = (const float*)d_in[2];  // (8, 2048, 2048)

  // ws layout (448 MiB):
  //   xb  bf16 [32768][2048]     128 MiB @ 0
  //   w1t bf16 [8][4096][2048]   128 MiB @ 128M
  //   w2t bf16 [8][2048][2048]    64 MiB @ 256M
  //   act bf16 [8][4096][2048]   128 MiB @ 320M
  char* ws = (char*)d_ws;
  bf16_t* xb = (bf16_t*)(ws);
  bf16_t* w1t = (bf16_t*)(ws + (size_t)134217728);
  bf16_t* w2t = (bf16_t*)(ws + (size_t)268435456);
  bf16_t* act = (bf16_t*)(ws + (size_t)335544320);

  const long n4 = (long)E_EXPERTS * TPE * KD / 4;
  cvt_f32_bf16_kernel<<<2048, 256, 0, stream>>>(hs, xb, n4);
  transpose_cvt_kernel<<<dim3(64, 32, 8), 256, 0, stream>>>(w1, w1t, 2048, 4096);
  transpose_cvt_kernel<<<dim3(32, 32, 8), 256, 0, stream>>>(w2, w2t, 2048, 2048);
  // G1: virtual N=4096 -> NTN=16; grid 8*32*16 = 4096
  moe_gemm_tlp_kernel<true, 16><<<4096, 512, 0, stream>>>(xb, w1t, (void*)act);
  // G2: N=2048 -> NTN=8; grid 8*32*8 = 2048
  moe_gemm_tlp_kernel<false, 8><<<2048, 512, 0, stream>>>(act, w2t, d_out);
}